// Round 7
// baseline (156.774 us; speedup 1.0000x reference)
//
#include <hip/hip_runtime.h>
#include <hip/hip_bf16.h>

#define L 96
#define CH 7
#define K_FEAT 7328
#define KPAD 7360           // 64 * 115 (zero-padded K)
#define K8 (KPAD / 8)       // 920 ushort8-chunks per row
#define KT64 115            // K-steps of 64
#define Q_END 4752          // 96 + 4656
#define PRED 720
#define NPAD 768
#define BATCH 256
#define M_TOT (BATCH * CH)  // 1792
#define NSPLIT 6
#define NTILE (14 * 6)                  // 84 (m,n) tiles
#define W_BLKS (NPAD * K8 / 256)        // 2760
#define TAB_BLKS ((K_FEAT + 255) / 256) // 29

typedef __attribute__((ext_vector_type(8))) short bf16x8;
typedef __attribute__((ext_vector_type(4))) float f32x4;

// ---------------- ws layout (bytes) ----------------
#define SZ_A    ((size_t)M_TOT * KPAD * 2)           // 26,378,240
#define SZ_W    ((size_t)NPAD * KPAD * 2)            // 11,304,960
#define SZ_PS   ((size_t)NSPLIT * M_TOT * NPAD * 4)  // 33,030,144
#define OFF_AH  ((size_t)0)
#define OFF_WH  (OFF_AH + SZ_A)
#define OFF_PS  (OFF_WH + SZ_W)
#define OFF_TAB (OFF_PS + SZ_PS)
#define OFF_CNT (OFF_TAB + (size_t)K_FEAT * 8)
#define WS_REQ  (OFF_CNT + (size_t)NTILE * 4)        // ~70.8 MB

static __device__ __forceinline__ unsigned short f2bf(float f) {
    __hip_bfloat16 h = __float2bfloat16(f);
    return *(unsigned short*)&h;
}

// async 16B global -> LDS (dest = wave-uniform base + lane*16)
static __device__ __forceinline__ void async_cp16(const unsigned short* g, unsigned short* l) {
    __builtin_amdgcn_global_load_lds(
        (const __attribute__((address_space(1))) unsigned int*)g,
        (__attribute__((address_space(3))) unsigned int*)l, 16, 0, 0);
}

// feature k -> index triple (t1,t2,t3), xv[96]=1.0 sentinel
static __device__ ushort4 feat_idx(int k) {
    unsigned short t1 = 96, t2 = 96, t3 = 0;
    if (k < L) {
        t3 = (unsigned short)k;
    } else if (k < Q_END) {
        int r = k - L;
        int i = 0, base = 0;
        while (base + (L - i) <= r) { base += L - i; ++i; }
        t2 = (unsigned short)i;
        t3 = (unsigned short)(i + (r - base));
    } else {
        int r = k - Q_END;
        int base = 0;
        for (int i = 0; i < CH; ++i) {
            for (int j = i; j < CH; ++j) {
                int len = L - j;
                if (r < base + len) {
                    return make_ushort4((unsigned short)i, (unsigned short)j,
                                        (unsigned short)(j + (r - base)), 0);
                }
                base += len;
            }
        }
    }
    return make_ushort4(t1, t2, t3, 0);
}

// Streaming prep: W bf16 split (padded) + index table + tile-counter zeroing.
__global__ __launch_bounds__(256) void prep1(
    const float* __restrict__ W, unsigned short* __restrict__ Wh,
    ushort4* __restrict__ tab, unsigned int* __restrict__ cnt) {
    const int bid = blockIdx.x;
    const int tid = threadIdx.x;
    if (bid < W_BLKS) {
        int gid = bid * 256 + tid;                 // exact: NPAD*K8
        int n = gid / K8, ch8 = gid - n * K8;
        int k = ch8 * 8;
        unsigned short o[8];
        #pragma unroll
        for (int j = 0; j < 8; ++j) {
            int kk = k + j;
            float v = (n < PRED && kk < K_FEAT) ? W[(size_t)n * K_FEAT + kk] : 0.0f;
            o[j] = f2bf(v);
        }
        *(uint4*)&Wh[(size_t)n * KPAD + k] = *(uint4*)o;
    } else if (bid < W_BLKS + TAB_BLKS) {
        int k = (bid - W_BLKS) * 256 + tid;
        if (k < K_FEAT) tab[k] = feat_idx(k);
    } else {
        if (tid < NTILE) cnt[tid] = 0u;
    }
}

// Featgen: 4 blocks per batch; each thread emits 8 consecutive k (16B store).
__global__ __launch_bounds__(256) void featgen4(
    const float* __restrict__ x, const ushort4* __restrict__ tab,
    unsigned short* __restrict__ Ah) {
    __shared__ float xl[CH][L + 1];   // 2,716 B
    const int b = blockIdx.x >> 2;
    const int part = blockIdx.x & 3;
    const int tid = threadIdx.x;

    for (int i = tid; i < L * CH; i += 256) {
        int t = i / CH, c = i - t * CH;
        xl[c][t] = x[(size_t)b * L * CH + i];
    }
    if (tid < CH) xl[tid][L] = 1.0f;
    __syncthreads();

    const int span = CH * K8 / 4;     // 1610 chunks per part
    unsigned short* Ab = Ah + (size_t)b * CH * KPAD;
    const int q1 = (part + 1) * span;
    for (int q = part * span + tid; q < q1; q += 256) {
        int c = q / K8, ch8 = q - c * K8;
        int k = ch8 * 8;
        unsigned short o[8];
        #pragma unroll
        for (int j = 0; j < 8; ++j) {
            int kk = k + j;
            float v = 0.0f;
            if (kk < K_FEAT) {
                ushort4 t = tab[kk];
                v = xl[c][t.x] * xl[c][t.y] * xl[c][t.z];
            }
            o[j] = f2bf(v);
        }
        *(uint4*)&Ab[(size_t)c * KPAD + k] = *(uint4*)o;
    }
}

// Single-MFMA bf16 GEMM, BK=64, double-buffered 2-phase pipeline,
// fused last-block K-reduction (ticket pattern) writing out+bias.
__global__ __launch_bounds__(256, 2) void gemm3(
    const unsigned short* __restrict__ Ah, const unsigned short* __restrict__ Wh,
    const float* __restrict__ bias, float* __restrict__ ps,
    unsigned int* __restrict__ cnt, float* __restrict__ out) {
    __shared__ unsigned short S[2][2][128 * 64];   // [buf][A,W] = 64 KB
    __shared__ int ticket_s;

    const int tid = threadIdx.x;
    const int lane = tid & 63;
    const int w = tid >> 6;            // 0..3
    const int wr = w >> 1, wc = w & 1; // wave 64x64 sub-tile

    // XCD-aware bijective swizzle: 504 blocks = 8 XCDs x 63
    const int id = blockIdx.x;
    const int nid = (id & 7) * 63 + (id >> 3);
    const int bx = nid % 14;
    const int rest = nid / 14;
    const int by = rest % 6;
    const int bz = rest / 6;
    const int m0 = bx * 128;
    const int n0 = by * 128;
    const int kt0 = (KT64 * bz) / NSPLIT;
    const int kt1 = (KT64 * (bz + 1)) / NSPLIT;

    // ---- staging: per wave 4 cp16 each for A and W; rows [w*32, w*32+32) ----
    const int cg = (lane & 7) ^ (lane >> 3);
    const unsigned short* gA[4];
    const unsigned short* gW[4];
    #pragma unroll
    for (int q = 0; q < 4; ++q) {
        int row = w * 32 + q * 8 + (lane >> 3);
        gA[q] = Ah + (size_t)(m0 + row) * KPAD + cg * 8 + kt0 * 64;
        gW[q] = Wh + (size_t)(n0 + row) * KPAD + cg * 8 + kt0 * 64;
    }

#define STAGE(B) do { \
        _Pragma("unroll") \
        for (int q = 0; q < 4; ++q) { \
            async_cp16(gA[q], &S[B][0][(w * 256 + q * 64) * 8]); \
            async_cp16(gW[q], &S[B][1][(w * 256 + q * 64) * 8]); \
            gA[q] += 64; gW[q] += 64; \
        } \
    } while (0)

    // ---- fragment read byte-offsets (same XOR involution) ----
    const int lr = lane & 15;
    const int ck = lane >> 4;
    int offA[4][2], offW[4][2];
    #pragma unroll
    for (int mi = 0; mi < 4; ++mi) {
        int r = wr * 64 + mi * 16 + lr;
        #pragma unroll
        for (int h = 0; h < 2; ++h)
            offA[mi][h] = r * 128 + (((h * 4 + ck) ^ (r & 7)) << 4);
    }
    #pragma unroll
    for (int ni = 0; ni < 4; ++ni) {
        int r = wc * 64 + ni * 16 + lr;
        #pragma unroll
        for (int h = 0; h < 2; ++h)
            offW[ni][h] = r * 128 + (((h * 4 + ck) ^ (r & 7)) << 4);
    }

    f32x4 acc[4][4] = {};

    STAGE(0);
    __syncthreads();
    int cur = 0;
    for (int kt = kt0; kt < kt1; ++kt) {
        if (kt + 1 < kt1) STAGE(cur ^ 1);

        const char* baseA = (const char*)S[cur][0];
        const char* baseW = (const char*)S[cur][1];
        bf16x8 ah[4][2], wh[4][2];
        #pragma unroll
        for (int mi = 0; mi < 4; ++mi) {
            ah[mi][0] = *(const bf16x8*)(baseA + offA[mi][0]);
            ah[mi][1] = *(const bf16x8*)(baseA + offA[mi][1]);
        }
        #pragma unroll
        for (int ni = 0; ni < 4; ++ni) {
            wh[ni][0] = *(const bf16x8*)(baseW + offW[ni][0]);
            wh[ni][1] = *(const bf16x8*)(baseW + offW[ni][1]);
        }
        #pragma unroll
        for (int mi = 0; mi < 4; ++mi) {
            #pragma unroll
            for (int ni = 0; ni < 4; ++ni) {
                acc[mi][ni] = __builtin_amdgcn_mfma_f32_16x16x32_bf16(ah[mi][0], wh[ni][0], acc[mi][ni], 0, 0, 0);
                acc[mi][ni] = __builtin_amdgcn_mfma_f32_16x16x32_bf16(ah[mi][1], wh[ni][1], acc[mi][ni], 0, 0, 0);
            }
        }
        __syncthreads();
        cur ^= 1;
    }
#undef STAGE

    // ---- write psum slice ----
    {
        float* pb = ps + (size_t)bz * M_TOT * NPAD;
        #pragma unroll
        for (int mi = 0; mi < 4; ++mi) {
            #pragma unroll
            for (int ni = 0; ni < 4; ++ni) {
                const int n = n0 + wc * 64 + ni * 16 + lr;
                const int mr = m0 + wr * 64 + mi * 16 + ck * 4;
                #pragma unroll
                for (int r = 0; r < 4; ++r) {
                    pb[(size_t)(mr + r) * NPAD + n] = acc[mi][ni][r];
                }
            }
        }
    }

    // ---- ticket: last block of this (bx,by) tile reduces all 6 slices ----
    __threadfence();                     // release psum stores device-wide
    __syncthreads();
    if (tid == 0) ticket_s = (int)atomicAdd(&cnt[bx * 6 + by], 1u);
    __syncthreads();
    if (ticket_s != NSPLIT - 1) return;
    __threadfence();                     // acquire other slices

    #pragma unroll
    for (int mi = 0; mi < 4; ++mi) {
        #pragma unroll
        for (int ni = 0; ni < 4; ++ni) {
            const int n = n0 + wc * 64 + ni * 16 + lr;
            if (n >= PRED) continue;
            const int mr = m0 + wr * 64 + mi * 16 + ck * 4;
            const float bv = bias[n];
            float tot[4] = {bv, bv, bv, bv};
            #pragma unroll
            for (int s = 0; s < NSPLIT; ++s) {       // fixed order -> deterministic
                const float* pb = ps + (size_t)s * M_TOT * NPAD + n;
                #pragma unroll
                for (int r = 0; r < 4; ++r)
                    tot[r] += pb[(size_t)(mr + r) * NPAD];
            }
            #pragma unroll
            for (int r = 0; r < 4; ++r) {
                const int m = mr + r;
                const int b = m / CH, c = m - b * CH;
                out[((size_t)b * PRED + n) * CH + c] = tot[r];
            }
        }
    }
}

// ================= fallback (round-1 vector kernel, proven) =================
#define BM 64
#define BN 64
#define BK 32
#define XSTRIDE 101

__global__ void build_table(ushort4* __restrict__ tab) {
    int k = blockIdx.x * blockDim.x + threadIdx.x;
    if (k < K_FEAT) tab[k] = feat_idx(k);
}

__global__ __launch_bounds__(256) void fused_poly_gemm(
    const float* __restrict__ x, const float* __restrict__ W,
    const float* __restrict__ bias, const ushort4* __restrict__ tab,
    float* __restrict__ out) {
    __shared__ float xt[BM][XSTRIDE];
    __shared__ float At[BK][BM];
    __shared__ float Wt[BK][BN];

    const int tid = threadIdx.x;
    const int m0 = blockIdx.x * BM;
    const int n0 = blockIdx.y * BN;

    for (int idx = tid; idx < BM * L; idx += 256) {
        int r = idx / L, t = idx - r * L;
        int m = m0 + r;
        int b = m / CH, c = m - b * CH;
        xt[r][t] = x[(b * L + t) * CH + c];
    }
    if (tid < BM) xt[tid][96] = 1.0f;
    __syncthreads();

    const int tm = tid & 15;
    const int tn = tid >> 4;
    float acc[4][4] = {};

    for (int k0 = 0; k0 < K_FEAT; k0 += BK) {
        #pragma unroll
        for (int q = tid; q < 512; q += 256) {
            int n = q >> 3, kq = q & 7;
            float4 wv;
            if (n0 + n < PRED) wv = *(const float4*)&W[(size_t)(n0 + n) * K_FEAT + k0 + kq * 4];
            else wv = make_float4(0.f, 0.f, 0.f, 0.f);
            Wt[kq * 4 + 0][n] = wv.x; Wt[kq * 4 + 1][n] = wv.y;
            Wt[kq * 4 + 2][n] = wv.z; Wt[kq * 4 + 3][n] = wv.w;
        }
        {
            int k = tid >> 3, mg = tid & 7;
            ushort4 e = tab[k0 + k];
            float p[8];
            #pragma unroll
            for (int mm = 0; mm < 8; ++mm) {
                int m = mg * 8 + mm;
                p[mm] = xt[m][e.x] * xt[m][e.y] * xt[m][e.z];
            }
            *(float4*)&At[k][mg * 8]     = make_float4(p[0], p[1], p[2], p[3]);
            *(float4*)&At[k][mg * 8 + 4] = make_float4(p[4], p[5], p[6], p[7]);
        }
        __syncthreads();
        #pragma unroll 8
        for (int k = 0; k < BK; ++k) {
            float4 a = *(const float4*)&At[k][tm * 4];
            float4 wv = *(const float4*)&Wt[k][tn * 4];
            acc[0][0] = fmaf(a.x, wv.x, acc[0][0]); acc[0][1] = fmaf(a.x, wv.y, acc[0][1]);
            acc[0][2] = fmaf(a.x, wv.z, acc[0][2]); acc[0][3] = fmaf(a.x, wv.w, acc[0][3]);
            acc[1][0] = fmaf(a.y, wv.x, acc[1][0]); acc[1][1] = fmaf(a.y, wv.y, acc[1][1]);
            acc[1][2] = fmaf(a.y, wv.z, acc[1][2]); acc[1][3] = fmaf(a.y, wv.w, acc[1][3]);
            acc[2][0] = fmaf(a.z, wv.x, acc[2][0]); acc[2][1] = fmaf(a.z, wv.y, acc[2][1]);
            acc[2][2] = fmaf(a.z, wv.z, acc[2][2]); acc[2][3] = fmaf(a.z, wv.w, acc[2][3]);
            acc[3][0] = fmaf(a.w, wv.x, acc[3][0]); acc[3][1] = fmaf(a.w, wv.y, acc[3][1]);
            acc[3][2] = fmaf(a.w, wv.z, acc[3][2]); acc[3][3] = fmaf(a.w, wv.w, acc[3][3]);
        }
        __syncthreads();
    }
    #pragma unroll
    for (int i = 0; i < 4; ++i) {
        int m = m0 + tm * 4 + i;
        int b = m / CH, c = m - b * CH;
        #pragma unroll
        for (int j = 0; j < 4; ++j) {
            int n = n0 + tn * 4 + j;
            if (n < PRED) out[((size_t)b * PRED + n) * CH + c] = acc[i][j] + bias[n];
        }
    }
}

extern "C" void kernel_launch(void* const* d_in, const int* in_sizes, int n_in,
                              void* d_out, int out_size, void* d_ws, size_t ws_size,
                              hipStream_t stream) {
    const float* x    = (const float*)d_in[0];
    const float* W    = (const float*)d_in[1];
    const float* bias = (const float*)d_in[2];
    float* out = (float*)d_out;
    char* ws = (char*)d_ws;

    if (ws_size >= WS_REQ) {
        unsigned short* Ah = (unsigned short*)(ws + OFF_AH);
        unsigned short* Wh = (unsigned short*)(ws + OFF_WH);
        float* psum = (float*)(ws + OFF_PS);
        ushort4* tab = (ushort4*)(ws + OFF_TAB);
        unsigned int* cnt = (unsigned int*)(ws + OFF_CNT);

        hipLaunchKernelGGL(prep1, dim3(W_BLKS + TAB_BLKS + 1), dim3(256), 0, stream,
                           W, Wh, tab, cnt);
        hipLaunchKernelGGL(featgen4, dim3(BATCH * 4), dim3(256), 0, stream, x, tab, Ah);
        hipLaunchKernelGGL(gemm3, dim3(NTILE * NSPLIT), dim3(256), 0, stream,
                           Ah, Wh, bias, psum, cnt, out);
    } else {
        ushort4* tab = (ushort4*)ws;
        hipLaunchKernelGGL(build_table, dim3((K_FEAT + 255) / 256), dim3(256), 0, stream, tab);
        dim3 grid(M_TOT / BM, (PRED + BN - 1) / BN);
        hipLaunchKernelGGL(fused_poly_gemm, grid, dim3(256), 0, stream, x, W, bias, tab, out);
    }
}

// Round 8
// 66.554 us; speedup vs baseline: 2.3556x; 2.3556x over previous
//
#include <hip/hip_runtime.h>
#include <hip/hip_bf16.h>

#define L 96
#define CH 7
#define K_FEAT 7328
#define KPAD 7360           // 64 * 115 (zero-padded K)
#define K8 (KPAD / 8)       // 920 ushort8-chunks per row
#define KT64 115            // K-steps of 64
#define Q_END 4752          // 96 + 4656
#define PRED 720
#define NPAD 768
#define BATCH 256
#define M_TOT (BATCH * CH)  // 1792
#define NSPLIT 6
#define W_BLKS (NPAD * K8 / 256)   // 2760
#define FEAT_BLKS (BATCH * 4)      // 1024 (4 parts per batch)

typedef __attribute__((ext_vector_type(8))) short bf16x8;
typedef __attribute__((ext_vector_type(4))) float f32x4;

// ---------------- ws layout (bytes) ----------------
#define SZ_A    ((size_t)M_TOT * KPAD * 2)           // 26,378,240
#define SZ_W    ((size_t)NPAD * KPAD * 2)            // 11,304,960
#define SZ_PS   ((size_t)NSPLIT * M_TOT * NPAD * 4)  // 33,030,144
#define OFF_AH  ((size_t)0)
#define OFF_WH  (OFF_AH + SZ_A)
#define OFF_PS  (OFF_WH + SZ_W)
#define WS_REQ  (OFF_PS + SZ_PS)                     // ~70.7 MB

static __device__ __forceinline__ unsigned short f2bf(float f) {
    __hip_bfloat16 h = __float2bfloat16(f);
    return *(unsigned short*)&h;
}

// async 16B global -> LDS (dest = wave-uniform base + lane*16)
static __device__ __forceinline__ void async_cp16(const unsigned short* g, unsigned short* l) {
    __builtin_amdgcn_global_load_lds(
        (const __attribute__((address_space(1))) unsigned int*)g,
        (__attribute__((address_space(3))) unsigned int*)l, 16, 0, 0);
}

// feature k -> index triple (t1,t2,t3), xv[96]=1.0 sentinel
static __device__ ushort4 feat_idx(int k) {
    unsigned short t1 = 96, t2 = 96, t3 = 0;
    if (k < L) {
        t3 = (unsigned short)k;
    } else if (k < Q_END) {
        int r = k - L;
        int i = 0, base = 0;
        while (base + (L - i) <= r) { base += L - i; ++i; }
        t2 = (unsigned short)i;
        t3 = (unsigned short)(i + (r - base));
    } else {
        int r = k - Q_END;
        int base = 0;
        for (int i = 0; i < CH; ++i) {
            for (int j = i; j < CH; ++j) {
                int len = L - j;
                if (r < base + len) {
                    return make_ushort4((unsigned short)i, (unsigned short)j,
                                        (unsigned short)(j + (r - base)), 0);
                }
                base += len;
            }
        }
    }
    return make_ushort4(t1, t2, t3, 0);
}

// advance (t1,t2,t3) by one feature index (enumeration order of feat_idx)
static __device__ __forceinline__ void adv_idx(int& t1, int& t2, int& t3) {
    if (t1 == 96) {
        if (t2 == 96) {                       // linear
            if (t3 < L - 1) ++t3; else { t2 = 0; t3 = 0; }
        } else {                              // quadratic (i=t2, t3 in [i,95])
            if (t3 < L - 1) ++t3;
            else if (t2 < L - 1) { ++t2; t3 = t2; }
            else { t1 = 0; t2 = 0; t3 = 0; }  // -> cubic (0,0,0)
        }
    } else {                                  // cubic (i=t1, j=t2, t3 in [j,95])
        if (t3 < L - 1) ++t3;
        else if (t2 < CH - 1) { ++t2; t3 = t2; }
        else { ++t1; t2 = t1; t3 = t1; }
    }
}

// One launch: blocks [0,FEAT_BLKS) = featgen (tab-free, incremental indices);
//             blocks [FEAT_BLKS, FEAT_BLKS+W_BLKS) = W bf16 split (padded).
__global__ __launch_bounds__(256) void prep_all2(
    const float* __restrict__ x, const float* __restrict__ W,
    unsigned short* __restrict__ Ah, unsigned short* __restrict__ Wh) {
    __shared__ float xl[CH][L + 1];   // 2,716 B
    const int bid = blockIdx.x;
    const int tid = threadIdx.x;

    if (bid < FEAT_BLKS) {
        const int b = bid >> 2;
        const int part = bid & 3;
        for (int i = tid; i < L * CH; i += 256) {
            int t = i / CH, c = i - t * CH;
            xl[c][t] = x[(size_t)b * L * CH + i];
        }
        if (tid < CH) xl[tid][L] = 1.0f;
        __syncthreads();

        const int span = CH * K8 / 4;     // 1610 chunks per part
        unsigned short* Ab = Ah + (size_t)b * CH * KPAD;
        const int q1 = (part + 1) * span;
        for (int q = part * span + tid; q < q1; q += 256) {
            int c = q / K8, ch8 = q - c * K8;
            int k = ch8 * 8;
            ushort4 e0 = feat_idx(k);
            int t1 = e0.x, t2 = e0.y, t3 = e0.z;
            unsigned short o[8];
            #pragma unroll
            for (int j = 0; j < 8; ++j) {
                int kk = k + j;
                float v = 0.0f;
                if (kk < K_FEAT) v = xl[c][t1] * xl[c][t2] * xl[c][t3];
                o[j] = f2bf(v);
                adv_idx(t1, t2, t3);
            }
            *(uint4*)&Ab[(size_t)c * KPAD + k] = *(uint4*)o;
        }
    } else {
        int gid = (bid - FEAT_BLKS) * 256 + tid;   // exact: NPAD*K8
        int n = gid / K8, ch8 = gid - n * K8;
        int k = ch8 * 8;
        unsigned short o[8];
        #pragma unroll
        for (int j = 0; j < 8; ++j) {
            int kk = k + j;
            float v = (n < PRED && kk < K_FEAT) ? W[(size_t)n * K_FEAT + kk] : 0.0f;
            o[j] = f2bf(v);
        }
        *(uint4*)&Wh[(size_t)n * KPAD + k] = *(uint4*)o;
    }
}

// Single-MFMA bf16 GEMM, BK=64, double-buffered 2-phase pipeline.
// 128x128 tile, 256 threads (4 waves 2x2), wave tile 64x64, K-split, XCD swizzle.
// (byte-identical to the round-6 proven kernel)
__global__ __launch_bounds__(256, 2) void gemm2(
    const unsigned short* __restrict__ Ah, const unsigned short* __restrict__ Wh,
    float* __restrict__ ps) {
    __shared__ unsigned short S[2][2][128 * 64];   // [buf][A,W] = 64 KB

    const int tid = threadIdx.x;
    const int lane = tid & 63;
    const int w = tid >> 6;            // 0..3
    const int wr = w >> 1, wc = w & 1; // wave 64x64 sub-tile

    // XCD-aware bijective swizzle: 504 blocks = 8 XCDs x 63
    const int id = blockIdx.x;
    const int nid = (id & 7) * 63 + (id >> 3);
    const int bx = nid % 14;
    const int rest = nid / 14;
    const int by = rest % 6;
    const int bz = rest / 6;
    const int m0 = bx * 128;
    const int n0 = by * 128;
    const int kt0 = (KT64 * bz) / NSPLIT;
    const int kt1 = (KT64 * (bz + 1)) / NSPLIT;

    // ---- staging: per wave 4 cp16 each for A and W; rows [w*32, w*32+32) ----
    const int cg = (lane & 7) ^ (lane >> 3);
    const unsigned short* gA[4];
    const unsigned short* gW[4];
    #pragma unroll
    for (int q = 0; q < 4; ++q) {
        int row = w * 32 + q * 8 + (lane >> 3);
        gA[q] = Ah + (size_t)(m0 + row) * KPAD + cg * 8 + kt0 * 64;
        gW[q] = Wh + (size_t)(n0 + row) * KPAD + cg * 8 + kt0 * 64;
    }

#define STAGE(B) do { \
        _Pragma("unroll") \
        for (int q = 0; q < 4; ++q) { \
            async_cp16(gA[q], &S[B][0][(w * 256 + q * 64) * 8]); \
            async_cp16(gW[q], &S[B][1][(w * 256 + q * 64) * 8]); \
            gA[q] += 64; gW[q] += 64; \
        } \
    } while (0)

    // ---- fragment read byte-offsets (same XOR involution) ----
    const int lr = lane & 15;
    const int ck = lane >> 4;
    int offA[4][2], offW[4][2];
    #pragma unroll
    for (int mi = 0; mi < 4; ++mi) {
        int r = wr * 64 + mi * 16 + lr;
        #pragma unroll
        for (int h = 0; h < 2; ++h)
            offA[mi][h] = r * 128 + (((h * 4 + ck) ^ (r & 7)) << 4);
    }
    #pragma unroll
    for (int ni = 0; ni < 4; ++ni) {
        int r = wc * 64 + ni * 16 + lr;
        #pragma unroll
        for (int h = 0; h < 2; ++h)
            offW[ni][h] = r * 128 + (((h * 4 + ck) ^ (r & 7)) << 4);
    }

    f32x4 acc[4][4] = {};

    STAGE(0);
    __syncthreads();
    int cur = 0;
    for (int kt = kt0; kt < kt1; ++kt) {
        if (kt + 1 < kt1) STAGE(cur ^ 1);

        const char* baseA = (const char*)S[cur][0];
        const char* baseW = (const char*)S[cur][1];
        bf16x8 ah[4][2], wh[4][2];
        #pragma unroll
        for (int mi = 0; mi < 4; ++mi) {
            ah[mi][0] = *(const bf16x8*)(baseA + offA[mi][0]);
            ah[mi][1] = *(const bf16x8*)(baseA + offA[mi][1]);
        }
        #pragma unroll
        for (int ni = 0; ni < 4; ++ni) {
            wh[ni][0] = *(const bf16x8*)(baseW + offW[ni][0]);
            wh[ni][1] = *(const bf16x8*)(baseW + offW[ni][1]);
        }
        #pragma unroll
        for (int mi = 0; mi < 4; ++mi) {
            #pragma unroll
            for (int ni = 0; ni < 4; ++ni) {
                acc[mi][ni] = __builtin_amdgcn_mfma_f32_16x16x32_bf16(ah[mi][0], wh[ni][0], acc[mi][ni], 0, 0, 0);
                acc[mi][ni] = __builtin_amdgcn_mfma_f32_16x16x32_bf16(ah[mi][1], wh[ni][1], acc[mi][ni], 0, 0, 0);
            }
        }
        __syncthreads();
        cur ^= 1;
    }
#undef STAGE

    // ---- epilogue: plain stores to psum slice ----
    float* pb = ps + (size_t)bz * M_TOT * NPAD;
    #pragma unroll
    for (int mi = 0; mi < 4; ++mi) {
        #pragma unroll
        for (int ni = 0; ni < 4; ++ni) {
            const int n = n0 + wc * 64 + ni * 16 + lr;
            const int mr = m0 + wr * 64 + mi * 16 + ck * 4;
            #pragma unroll
            for (int r = 0; r < 4; ++r) {
                pb[(size_t)(mr + r) * NPAD + n] = acc[mi][ni][r];
            }
        }
    }
}

// out[b][p][c] = sum_s psum[s][b*CH+c][p] + bias[p]   (one thread per (b,p))
__global__ __launch_bounds__(256) void reduce_k(
    const float* __restrict__ ps, const float* __restrict__ bias,
    float* __restrict__ out) {
    int gid = blockIdx.x * 256 + threadIdx.x;   // exact grid: BATCH*PRED
    int b = gid / PRED, p = gid - b * PRED;
    float bv = bias[p];
    float o[CH];
    #pragma unroll
    for (int c = 0; c < CH; ++c) o[c] = bv;
    #pragma unroll
    for (int s = 0; s < NSPLIT; ++s) {
        const float* pb = ps + (size_t)s * M_TOT * NPAD + (size_t)b * CH * NPAD + p;
        #pragma unroll
        for (int c = 0; c < CH; ++c) o[c] += pb[(size_t)c * NPAD];
    }
    float* ob = out + (size_t)gid * CH;
    #pragma unroll
    for (int c = 0; c < CH; ++c) ob[c] = o[c];
}

// ================= fallback (round-1 vector kernel, proven) =================
#define BM 64
#define BN 64
#define BK 32
#define XSTRIDE 101

__global__ void build_table(ushort4* __restrict__ tab) {
    int k = blockIdx.x * blockDim.x + threadIdx.x;
    if (k < K_FEAT) tab[k] = feat_idx(k);
}

__global__ __launch_bounds__(256) void fused_poly_gemm(
    const float* __restrict__ x, const float* __restrict__ W,
    const float* __restrict__ bias, const ushort4* __restrict__ tab,
    float* __restrict__ out) {
    __shared__ float xt[BM][XSTRIDE];
    __shared__ float At[BK][BM];
    __shared__ float Wt[BK][BN];

    const int tid = threadIdx.x;
    const int m0 = blockIdx.x * BM;
    const int n0 = blockIdx.y * BN;

    for (int idx = tid; idx < BM * L; idx += 256) {
        int r = idx / L, t = idx - r * L;
        int m = m0 + r;
        int b = m / CH, c = m - b * CH;
        xt[r][t] = x[(b * L + t) * CH + c];
    }
    if (tid < BM) xt[tid][96] = 1.0f;
    __syncthreads();

    const int tm = tid & 15;
    const int tn = tid >> 4;
    float acc[4][4] = {};

    for (int k0 = 0; k0 < K_FEAT; k0 += BK) {
        #pragma unroll
        for (int q = tid; q < 512; q += 256) {
            int n = q >> 3, kq = q & 7;
            float4 wv;
            if (n0 + n < PRED) wv = *(const float4*)&W[(size_t)(n0 + n) * K_FEAT + k0 + kq * 4];
            else wv = make_float4(0.f, 0.f, 0.f, 0.f);
            Wt[kq * 4 + 0][n] = wv.x; Wt[kq * 4 + 1][n] = wv.y;
            Wt[kq * 4 + 2][n] = wv.z; Wt[kq * 4 + 3][n] = wv.w;
        }
        {
            int k = tid >> 3, mg = tid & 7;
            ushort4 e = tab[k0 + k];
            float p[8];
            #pragma unroll
            for (int mm = 0; mm < 8; ++mm) {
                int m = mg * 8 + mm;
                p[mm] = xt[m][e.x] * xt[m][e.y] * xt[m][e.z];
            }
            *(float4*)&At[k][mg * 8]     = make_float4(p[0], p[1], p[2], p[3]);
            *(float4*)&At[k][mg * 8 + 4] = make_float4(p[4], p[5], p[6], p[7]);
        }
        __syncthreads();
        #pragma unroll 8
        for (int k = 0; k < BK; ++k) {
            float4 a = *(const float4*)&At[k][tm * 4];
            float4 wv = *(const float4*)&Wt[k][tn * 4];
            acc[0][0] = fmaf(a.x, wv.x, acc[0][0]); acc[0][1] = fmaf(a.x, wv.y, acc[0][1]);
            acc[0][2] = fmaf(a.x, wv.z, acc[0][2]); acc[0][3] = fmaf(a.x, wv.w, acc[0][3]);
            acc[1][0] = fmaf(a.y, wv.x, acc[1][0]); acc[1][1] = fmaf(a.y, wv.y, acc[1][1]);
            acc[1][2] = fmaf(a.y, wv.z, acc[1][2]); acc[1][3] = fmaf(a.y, wv.w, acc[1][3]);
            acc[2][0] = fmaf(a.z, wv.x, acc[2][0]); acc[2][1] = fmaf(a.z, wv.y, acc[2][1]);
            acc[2][2] = fmaf(a.z, wv.z, acc[2][2]); acc[2][3] = fmaf(a.z, wv.w, acc[2][3]);
            acc[3][0] = fmaf(a.w, wv.x, acc[3][0]); acc[3][1] = fmaf(a.w, wv.y, acc[3][1]);
            acc[3][2] = fmaf(a.w, wv.z, acc[3][2]); acc[3][3] = fmaf(a.w, wv.w, acc[3][3]);
        }
        __syncthreads();
    }
    #pragma unroll
    for (int i = 0; i < 4; ++i) {
        int m = m0 + tm * 4 + i;
        int b = m / CH, c = m - b * CH;
        #pragma unroll
        for (int j = 0; j < 4; ++j) {
            int n = n0 + tn * 4 + j;
            if (n < PRED) out[((size_t)b * PRED + n) * CH + c] = acc[i][j] + bias[n];
        }
    }
}

extern "C" void kernel_launch(void* const* d_in, const int* in_sizes, int n_in,
                              void* d_out, int out_size, void* d_ws, size_t ws_size,
                              hipStream_t stream) {
    const float* x    = (const float*)d_in[0];
    const float* W    = (const float*)d_in[1];
    const float* bias = (const float*)d_in[2];
    float* out = (float*)d_out;
    char* ws = (char*)d_ws;

    if (ws_size >= WS_REQ) {
        unsigned short* Ah = (unsigned short*)(ws + OFF_AH);
        unsigned short* Wh = (unsigned short*)(ws + OFF_WH);
        float* psum = (float*)(ws + OFF_PS);

        hipLaunchKernelGGL(prep_all2, dim3(FEAT_BLKS + W_BLKS), dim3(256), 0, stream,
                           x, W, Ah, Wh);
        hipLaunchKernelGGL(gemm2, dim3(14 * 6 * NSPLIT), dim3(256), 0, stream, Ah, Wh, psum);
        hipLaunchKernelGGL(reduce_k, dim3(BATCH * PRED / 256), dim3(256), 0, stream,
                           psum, bias, out);
    } else {
        ushort4* tab = (ushort4*)ws;
        hipLaunchKernelGGL(build_table, dim3((K_FEAT + 255) / 256), dim3(256), 0, stream, tab);
        dim3 grid(M_TOT / BM, (PRED + BN - 1) / BN);
        hipLaunchKernelGGL(fused_poly_gemm, grid, dim3(256), 0, stream, x, W, bias, tab, out);
    }
}

// Round 9
// 66.047 us; speedup vs baseline: 2.3737x; 1.0077x over previous
//
#include <hip/hip_runtime.h>
#include <hip/hip_bf16.h>

#define L 96
#define CH 7
#define K_FEAT 7328
#define KPAD 7360           // 64 * 115 (zero-padded K)
#define K8 (KPAD / 8)       // 920 ushort8-chunks per row
#define KT64 115            // K-steps of 64
#define Q_END 4752          // 96 + 4656
#define PRED 720
#define NPAD 768
#define BATCH 256
#define M_TOT (BATCH * CH)  // 1792
#define NSPLIT 6
#define W_BLKS (NPAD * K8 / 256)   // 2760
#define FEAT_BLKS (BATCH * 4)      // 1024 (4 parts per batch)

typedef __attribute__((ext_vector_type(8))) short bf16x8;
typedef __attribute__((ext_vector_type(4))) float f32x4;

// ---------------- ws layout (bytes) ----------------
#define SZ_A    ((size_t)M_TOT * KPAD * 2)           // 26,378,240
#define SZ_W    ((size_t)NPAD * KPAD * 2)            // 11,304,960
#define SZ_PS   ((size_t)NSPLIT * M_TOT * NPAD * 4)  // 33,030,144
#define OFF_AH  ((size_t)0)
#define OFF_WH  (OFF_AH + SZ_A)
#define OFF_PS  (OFF_WH + SZ_W)
#define WS_REQ  (OFF_PS + SZ_PS)                     // ~70.7 MB

static __device__ __forceinline__ unsigned short f2bf(float f) {
    __hip_bfloat16 h = __float2bfloat16(f);
    return *(unsigned short*)&h;
}

// async 16B global -> LDS (dest = wave-uniform base + lane*16)
static __device__ __forceinline__ void async_cp16(const unsigned short* g, unsigned short* l) {
    __builtin_amdgcn_global_load_lds(
        (const __attribute__((address_space(1))) unsigned int*)g,
        (__attribute__((address_space(3))) unsigned int*)l, 16, 0, 0);
}

// feature k -> index triple (t1,t2,t3), xv[96]=1.0 sentinel
static __device__ ushort4 feat_idx(int k) {
    unsigned short t1 = 96, t2 = 96, t3 = 0;
    if (k < L) {
        t3 = (unsigned short)k;
    } else if (k < Q_END) {
        int r = k - L;
        int i = 0, base = 0;
        while (base + (L - i) <= r) { base += L - i; ++i; }
        t2 = (unsigned short)i;
        t3 = (unsigned short)(i + (r - base));
    } else {
        int r = k - Q_END;
        int base = 0;
        for (int i = 0; i < CH; ++i) {
            for (int j = i; j < CH; ++j) {
                int len = L - j;
                if (r < base + len) {
                    return make_ushort4((unsigned short)i, (unsigned short)j,
                                        (unsigned short)(j + (r - base)), 0);
                }
                base += len;
            }
        }
    }
    return make_ushort4(t1, t2, t3, 0);
}

// advance (t1,t2,t3) by one feature index (enumeration order of feat_idx)
static __device__ __forceinline__ void adv_idx(int& t1, int& t2, int& t3) {
    if (t1 == 96) {
        if (t2 == 96) {                       // linear
            if (t3 < L - 1) ++t3; else { t2 = 0; t3 = 0; }
        } else {                              // quadratic (i=t2, t3 in [i,95])
            if (t3 < L - 1) ++t3;
            else if (t2 < L - 1) { ++t2; t3 = t2; }
            else { t1 = 0; t2 = 0; t3 = 0; }  // -> cubic (0,0,0)
        }
    } else {                                  // cubic (i=t1, j=t2, t3 in [j,95])
        if (t3 < L - 1) ++t3;
        else if (t2 < CH - 1) { ++t2; t3 = t2; }
        else { ++t1; t2 = t1; t3 = t1; }
    }
}

// One launch: blocks [0,FEAT_BLKS) = featgen (tab-free, incremental indices);
//             blocks [FEAT_BLKS, FEAT_BLKS+W_BLKS) = W bf16 split (padded).
__global__ __launch_bounds__(256) void prep_all2(
    const float* __restrict__ x, const float* __restrict__ W,
    unsigned short* __restrict__ Ah, unsigned short* __restrict__ Wh) {
    __shared__ float xl[CH][L + 1];   // 2,716 B
    const int bid = blockIdx.x;
    const int tid = threadIdx.x;

    if (bid < FEAT_BLKS) {
        const int b = bid >> 2;
        const int part = bid & 3;
        for (int i = tid; i < L * CH; i += 256) {
            int t = i / CH, c = i - t * CH;
            xl[c][t] = x[(size_t)b * L * CH + i];
        }
        if (tid < CH) xl[tid][L] = 1.0f;
        __syncthreads();

        const int span = CH * K8 / 4;     // 1610 chunks per part
        unsigned short* Ab = Ah + (size_t)b * CH * KPAD;
        const int q1 = (part + 1) * span;
        for (int q = part * span + tid; q < q1; q += 256) {
            int c = q / K8, ch8 = q - c * K8;
            int k = ch8 * 8;
            ushort4 e0 = feat_idx(k);
            int t1 = e0.x, t2 = e0.y, t3 = e0.z;
            unsigned short o[8];
            #pragma unroll
            for (int j = 0; j < 8; ++j) {
                int kk = k + j;
                float v = 0.0f;
                if (kk < K_FEAT) v = xl[c][t1] * xl[c][t2] * xl[c][t3];
                o[j] = f2bf(v);
                adv_idx(t1, t2, t3);
            }
            *(uint4*)&Ab[(size_t)c * KPAD + k] = *(uint4*)o;
        }
    } else {
        int gid = (bid - FEAT_BLKS) * 256 + tid;   // exact: NPAD*K8
        int n = gid / K8, ch8 = gid - n * K8;
        int k = ch8 * 8;
        unsigned short o[8];
        #pragma unroll
        for (int j = 0; j < 8; ++j) {
            int kk = k + j;
            float v = (n < PRED && kk < K_FEAT) ? W[(size_t)n * K_FEAT + kk] : 0.0f;
            o[j] = f2bf(v);
        }
        *(uint4*)&Wh[(size_t)n * KPAD + k] = *(uint4*)o;
    }
}

// Single-MFMA bf16 GEMM, BK=64, double-buffered, COUNTED-vmcnt pipeline:
// per K-step: STAGE(next) -> s_waitcnt vmcnt(8) (only cur's loads) ->
// bare s_barrier -> ds_read+MFMA -> bare s_barrier (no drain).
// 128x128 tile, 256 threads (4 waves 2x2), wave tile 64x64, K-split, XCD swizzle.
__global__ __launch_bounds__(256, 2) void gemm2(
    const unsigned short* __restrict__ Ah, const unsigned short* __restrict__ Wh,
    float* __restrict__ ps) {
    __shared__ unsigned short S[2][2][128 * 64];   // [buf][A,W] = 64 KB

    const int tid = threadIdx.x;
    const int lane = tid & 63;
    const int w = tid >> 6;            // 0..3
    const int wr = w >> 1, wc = w & 1; // wave 64x64 sub-tile

    // XCD-aware bijective swizzle: 504 blocks = 8 XCDs x 63
    const int id = blockIdx.x;
    const int nid = (id & 7) * 63 + (id >> 3);
    const int bx = nid % 14;
    const int rest = nid / 14;
    const int by = rest % 6;
    const int bz = rest / 6;
    const int m0 = bx * 128;
    const int n0 = by * 128;
    const int kt0 = (KT64 * bz) / NSPLIT;
    const int kt1 = (KT64 * (bz + 1)) / NSPLIT;

    // ---- staging: per wave 4 cp16 each for A and W; rows [w*32, w*32+32) ----
    const int cg = (lane & 7) ^ (lane >> 3);
    const unsigned short* gA[4];
    const unsigned short* gW[4];
    #pragma unroll
    for (int q = 0; q < 4; ++q) {
        int row = w * 32 + q * 8 + (lane >> 3);
        gA[q] = Ah + (size_t)(m0 + row) * KPAD + cg * 8 + kt0 * 64;
        gW[q] = Wh + (size_t)(n0 + row) * KPAD + cg * 8 + kt0 * 64;
    }

#define STAGE(B) do { \
        _Pragma("unroll") \
        for (int q = 0; q < 4; ++q) { \
            async_cp16(gA[q], &S[B][0][(w * 256 + q * 64) * 8]); \
            async_cp16(gW[q], &S[B][1][(w * 256 + q * 64) * 8]); \
            gA[q] += 64; gW[q] += 64; \
        } \
    } while (0)

    // ---- fragment read byte-offsets (same XOR involution) ----
    const int lr = lane & 15;
    const int ck = lane >> 4;
    int offA[4][2], offW[4][2];
    #pragma unroll
    for (int mi = 0; mi < 4; ++mi) {
        int r = wr * 64 + mi * 16 + lr;
        #pragma unroll
        for (int h = 0; h < 2; ++h)
            offA[mi][h] = r * 128 + (((h * 4 + ck) ^ (r & 7)) << 4);
    }
    #pragma unroll
    for (int ni = 0; ni < 4; ++ni) {
        int r = wc * 64 + ni * 16 + lr;
        #pragma unroll
        for (int h = 0; h < 2; ++h)
            offW[ni][h] = r * 128 + (((h * 4 + ck) ^ (r & 7)) << 4);
    }

    f32x4 acc[4][4] = {};

    STAGE(0);
    asm volatile("s_waitcnt vmcnt(0)" ::: "memory");
    __builtin_amdgcn_s_barrier();
    int cur = 0;
    for (int kt = kt0; kt < kt1; ++kt) {
        const bool has_next = (kt + 1 < kt1);
        if (has_next) {
            STAGE(cur ^ 1);
            // wait only for cur's 8 loads; next tile's 8 stay in flight
            asm volatile("s_waitcnt vmcnt(8)" ::: "memory");
        } else {
            asm volatile("s_waitcnt vmcnt(0)" ::: "memory");
        }
        __builtin_amdgcn_sched_barrier(0);
        __builtin_amdgcn_s_barrier();        // all waves: cur's LDS writes landed
        __builtin_amdgcn_sched_barrier(0);

        const char* baseA = (const char*)S[cur][0];
        const char* baseW = (const char*)S[cur][1];
        bf16x8 ah[4][2], wh[4][2];
        #pragma unroll
        for (int mi = 0; mi < 4; ++mi) {
            ah[mi][0] = *(const bf16x8*)(baseA + offA[mi][0]);
            ah[mi][1] = *(const bf16x8*)(baseA + offA[mi][1]);
        }
        #pragma unroll
        for (int ni = 0; ni < 4; ++ni) {
            wh[ni][0] = *(const bf16x8*)(baseW + offW[ni][0]);
            wh[ni][1] = *(const bf16x8*)(baseW + offW[ni][1]);
        }
        #pragma unroll
        for (int mi = 0; mi < 4; ++mi) {
            #pragma unroll
            for (int ni = 0; ni < 4; ++ni) {
                acc[mi][ni] = __builtin_amdgcn_mfma_f32_16x16x32_bf16(ah[mi][0], wh[ni][0], acc[mi][ni], 0, 0, 0);
                acc[mi][ni] = __builtin_amdgcn_mfma_f32_16x16x32_bf16(ah[mi][1], wh[ni][1], acc[mi][ni], 0, 0, 0);
            }
        }
        __builtin_amdgcn_s_barrier();        // all waves done reading cur (no drain)
        cur ^= 1;
    }
#undef STAGE

    // ---- epilogue: plain stores to psum slice ----
    float* pb = ps + (size_t)bz * M_TOT * NPAD;
    #pragma unroll
    for (int mi = 0; mi < 4; ++mi) {
        #pragma unroll
        for (int ni = 0; ni < 4; ++ni) {
            const int n = n0 + wc * 64 + ni * 16 + lr;
            const int mr = m0 + wr * 64 + mi * 16 + ck * 4;
            #pragma unroll
            for (int r = 0; r < 4; ++r) {
                pb[(size_t)(mr + r) * NPAD + n] = acc[mi][ni][r];
            }
        }
    }
}

// out[b][p][c] = sum_s psum[s][b*CH+c][p] + bias[p]   (one thread per (b,p))
__global__ __launch_bounds__(256) void reduce_k(
    const float* __restrict__ ps, const float* __restrict__ bias,
    float* __restrict__ out) {
    int gid = blockIdx.x * 256 + threadIdx.x;   // exact grid: BATCH*PRED
    int b = gid / PRED, p = gid - b * PRED;
    float bv = bias[p];
    float o[CH];
    #pragma unroll
    for (int c = 0; c < CH; ++c) o[c] = bv;
    #pragma unroll
    for (int s = 0; s < NSPLIT; ++s) {
        const float* pb = ps + (size_t)s * M_TOT * NPAD + (size_t)b * CH * NPAD + p;
        #pragma unroll
        for (int c = 0; c < CH; ++c) o[c] += pb[(size_t)c * NPAD];
    }
    float* ob = out + (size_t)gid * CH;
    #pragma unroll
    for (int c = 0; c < CH; ++c) ob[c] = o[c];
}

// ================= fallback (round-1 vector kernel, proven) =================
#define BM 64
#define BN 64
#define BK 32
#define XSTRIDE 101

__global__ void build_table(ushort4* __restrict__ tab) {
    int k = blockIdx.x * blockDim.x + threadIdx.x;
    if (k < K_FEAT) tab[k] = feat_idx(k);
}

__global__ __launch_bounds__(256) void fused_poly_gemm(
    const float* __restrict__ x, const float* __restrict__ W,
    const float* __restrict__ bias, const ushort4* __restrict__ tab,
    float* __restrict__ out) {
    __shared__ float xt[BM][XSTRIDE];
    __shared__ float At[BK][BM];
    __shared__ float Wt[BK][BN];

    const int tid = threadIdx.x;
    const int m0 = blockIdx.x * BM;
    const int n0 = blockIdx.y * BN;

    for (int idx = tid; idx < BM * L; idx += 256) {
        int r = idx / L, t = idx - r * L;
        int m = m0 + r;
        int b = m / CH, c = m - b * CH;
        xt[r][t] = x[(b * L + t) * CH + c];
    }
    if (tid < BM) xt[tid][96] = 1.0f;
    __syncthreads();

    const int tm = tid & 15;
    const int tn = tid >> 4;
    float acc[4][4] = {};

    for (int k0 = 0; k0 < K_FEAT; k0 += BK) {
        #pragma unroll
        for (int q = tid; q < 512; q += 256) {
            int n = q >> 3, kq = q & 7;
            float4 wv;
            if (n0 + n < PRED) wv = *(const float4*)&W[(size_t)(n0 + n) * K_FEAT + k0 + kq * 4];
            else wv = make_float4(0.f, 0.f, 0.f, 0.f);
            Wt[kq * 4 + 0][n] = wv.x; Wt[kq * 4 + 1][n] = wv.y;
            Wt[kq * 4 + 2][n] = wv.z; Wt[kq * 4 + 3][n] = wv.w;
        }
        {
            int k = tid >> 3, mg = tid & 7;
            ushort4 e = tab[k0 + k];
            float p[8];
            #pragma unroll
            for (int mm = 0; mm < 8; ++mm) {
                int m = mg * 8 + mm;
                p[mm] = xt[m][e.x] * xt[m][e.y] * xt[m][e.z];
            }
            *(float4*)&At[k][mg * 8]     = make_float4(p[0], p[1], p[2], p[3]);
            *(float4*)&At[k][mg * 8 + 4] = make_float4(p[4], p[5], p[6], p[7]);
        }
        __syncthreads();
        #pragma unroll 8
        for (int k = 0; k < BK; ++k) {
            float4 a = *(const float4*)&At[k][tm * 4];
            float4 wv = *(const float4*)&Wt[k][tn * 4];
            acc[0][0] = fmaf(a.x, wv.x, acc[0][0]); acc[0][1] = fmaf(a.x, wv.y, acc[0][1]);
            acc[0][2] = fmaf(a.x, wv.z, acc[0][2]); acc[0][3] = fmaf(a.x, wv.w, acc[0][3]);
            acc[1][0] = fmaf(a.y, wv.x, acc[1][0]); acc[1][1] = fmaf(a.y, wv.y, acc[1][1]);
            acc[1][2] = fmaf(a.y, wv.z, acc[1][2]); acc[1][3] = fmaf(a.y, wv.w, acc[1][3]);
            acc[2][0] = fmaf(a.z, wv.x, acc[2][0]); acc[2][1] = fmaf(a.z, wv.y, acc[2][1]);
            acc[2][2] = fmaf(a.z, wv.z, acc[2][2]); acc[2][3] = fmaf(a.z, wv.w, acc[2][3]);
            acc[3][0] = fmaf(a.w, wv.x, acc[3][0]); acc[3][1] = fmaf(a.w, wv.y, acc[3][1]);
            acc[3][2] = fmaf(a.w, wv.z, acc[3][2]); acc[3][3] = fmaf(a.w, wv.w, acc[3][3]);
        }
        __syncthreads();
    }
    #pragma unroll
    for (int i = 0; i < 4; ++i) {
        int m = m0 + tm * 4 + i;
        int b = m / CH, c = m - b * CH;
        #pragma unroll
        for (int j = 0; j < 4; ++j) {
            int n = n0 + tn * 4 + j;
            if (n < PRED) out[((size_t)b * PRED + n) * CH + c] = acc[i][j] + bias[n];
        }
    }
}

extern "C" void kernel_launch(void* const* d_in, const int* in_sizes, int n_in,
                              void* d_out, int out_size, void* d_ws, size_t ws_size,
                              hipStream_t stream) {
    const float* x    = (const float*)d_in[0];
    const float* W    = (const float*)d_in[1];
    const float* bias = (const float*)d_in[2];
    float* out = (float*)d_out;
    char* ws = (char*)d_ws;

    if (ws_size >= WS_REQ) {
        unsigned short* Ah = (unsigned short*)(ws + OFF_AH);
        unsigned short* Wh = (unsigned short*)(ws + OFF_WH);
        float* psum = (float*)(ws + OFF_PS);

        hipLaunchKernelGGL(prep_all2, dim3(FEAT_BLKS + W_BLKS), dim3(256), 0, stream,
                           x, W, Ah, Wh);
        hipLaunchKernelGGL(gemm2, dim3(14 * 6 * NSPLIT), dim3(256), 0, stream, Ah, Wh, psum);
        hipLaunchKernelGGL(reduce_k, dim3(BATCH * PRED / 256), dim3(256), 0, stream,
                           psum, bias, out);
    } else {
        ushort4* tab = (ushort4*)ws;
        hipLaunchKernelGGL(build_table, dim3((K_FEAT + 255) / 256), dim3(256), 0, stream, tab);
        dim3 grid(M_TOT / BM, (PRED + BN - 1) / BN);
        hipLaunchKernelGGL(fused_poly_gemm, grid, dim3(256), 0, stream, x, W, bias, tab, out);
    }
}